// Round 7
// baseline (13512.767 us; speedup 1.0000x reference)
//
#include <hip/hip_runtime.h>
#include <hip/hip_bf16.h>

// ---------------------------------------------------------------------------
// 3-layer original-paper GRU, B=128, T=128, I=512, H={512,1024,2048}.
// Round 7: fragment-major (FM) layouts + LDS-free GEMM.
//  - Every GEMM operand lives in fragment-major form FM[k/32][row][32] (bf16),
//    so an MFMA fragment load is one coalesced 1KB global_load_dwordx4 per
//    wave. No LDS, no __syncthreads, no vmcnt drains; compiler pipelines
//    loads with fine-grained vmcnt (m97 evidence). Raw s_barrier every 16
//    k-iters keeps waves aligned so shared A/B chunks stay L1-resident.
//  - Weights pre-shuffled once into FM (bf16); x pre-shuffled once; h and rh
//    are *written* in FM form by the epilogues (plus fp32 row-major h copy).
//  - Diagonal layer pipeline as R5 (proven): tick u = (layer l, t = u-l),
//    zr + n kernels per tick, h double-buffered by tick parity.
//  - Block: 128 rows x 64 cols, 8 waves (4 row-groups x 2 col-groups), wave
//    tile 32x32 (2x2 16x16x32 mfma), ~90 VGPR -> 2 blocks/CU.
// ---------------------------------------------------------------------------

typedef __attribute__((ext_vector_type(8))) short s16x8;
typedef __attribute__((ext_vector_type(4))) float f32x4;

__device__ __forceinline__ unsigned short f2b(float f) {
  unsigned int u = __float_as_uint(f);
  unsigned int r = (u + 0x7FFFu + ((u >> 16) & 1u)) >> 16;
  return (unsigned short)r;
}
__device__ __forceinline__ float sigmoidf_(float x) {
  return 1.0f / (1.0f + __expf(-x));
}
__device__ __forceinline__ float tanhf_(float x) {
  x = fminf(fmaxf(x, -15.0f), 15.0f);
  float e = __expf(-2.0f * x);
  return (1.0f - e) / (1.0f + e);
}

struct DiagP {
  const unsigned short* xFM;       // [T][I/32][128][32]
  const unsigned short* wzrIh[3];  // FM [inl/32][2H][32]
  const unsigned short* wzrHh[3];  // FM [H/32][2H][32]
  const unsigned short* wnIh[3];   // FM [inl/32][H][32]
  const unsigned short* wnHh[3];   // FM [H/32][H][32]
  const float* bias[3];            // [3H] f32
  float* hf[3][2];                 // fp32 row-major h, by tick parity
  unsigned short* hFM[3][2];       // bf16 FM h, by tick parity
  float* zb[3];                    // fp32 row-major z
  unsigned short* rhFM[3];         // bf16 FM r*h
  const float* mask;               // [B,T]
  float* out;                      // [B,3584]
};

// C[128x? tile] += A_FM @ W_FM^T for this wave's 32x32 slice.
// A: FM[kc][128][32]; W: FM[kc][N][32] (wStride = N*32).
__device__ __forceinline__ void frag_gemm(
    const unsigned short* __restrict__ A, const unsigned short* __restrict__ W,
    int kcCount, int wStride, int arow, int bcol, f32x4 acc[2][2]) {
  const int lane = threadIdx.x & 63;
  const int l16 = lane & 15, quad = lane >> 4;
  const unsigned short* a = A + (size_t)(arow + l16) * 32 + quad * 8;
  const unsigned short* b = W + (size_t)(bcol + l16) * 32 + quad * 8;
  for (int kc0 = 0; kc0 < kcCount; kc0 += 16) {
#pragma unroll 4
    for (int kk = 0; kk < 16; ++kk) {
      s16x8 a0 = *(const s16x8*)a;
      s16x8 a1 = *(const s16x8*)(a + 512);  // row +16
      s16x8 b0 = *(const s16x8*)b;
      s16x8 b1 = *(const s16x8*)(b + 512);  // col +16
      acc[0][0] =
          __builtin_amdgcn_mfma_f32_16x16x32_bf16(a0, b0, acc[0][0], 0, 0, 0);
      acc[0][1] =
          __builtin_amdgcn_mfma_f32_16x16x32_bf16(a0, b1, acc[0][1], 0, 0, 0);
      acc[1][0] =
          __builtin_amdgcn_mfma_f32_16x16x32_bf16(a1, b0, acc[1][0], 0, 0, 0);
      acc[1][1] =
          __builtin_amdgcn_mfma_f32_16x16x32_bf16(a1, b1, acc[1][1], 0, 0, 0);
      a += 4096;     // next k-chunk: 128 rows * 32
      b += wStride;  // next k-chunk: N rows * 32
    }
    __builtin_amdgcn_s_barrier();  // realign waves (no memory semantics used)
  }
}

// ---- zr: z/r gates for all active layers at tick u. 112 blocks. ----
__global__ __launch_bounds__(512) void diag_zr(DiagP p, int u) {
  const int blk = blockIdx.x;
  const int l = (blk < 16) ? 0 : ((blk < 48) ? 1 : 2);
  const int nt = blk - ((l == 0) ? 0 : ((l == 1) ? 16 : 48));
  const int t = u - l;
  if (t < 0 || t >= 128) return;
  const int H = 512 << l;
  const int inl = (l == 0) ? 512 : (512 << (l - 1));
  const int oldS = (u + 1) & 1;

  const unsigned short* A1 =
      (l == 0) ? p.xFM + (size_t)t * 65536 : p.hFM[l - 1][oldS];

  const int tid = threadIdx.x, wave = tid >> 6;
  const int wg = wave >> 1, wc = wave & 1;
  const int arow = wg * 32;
  const int bcol = nt * 64 + wc * 32;

  f32x4 acc[2][2] = {};
  frag_gemm(A1, p.wzrIh[l], inl >> 5, 2 * H * 32, arow, bcol, acc);
  frag_gemm(p.hFM[l][oldS], p.wzrHh[l], H >> 5, 2 * H * 32, arow, bcol, acc);

  const int lane = tid & 63, l16 = lane & 15, quad = lane >> 4;
  const float* hfo = p.hf[l][oldS];
#pragma unroll
  for (int ni = 0; ni < 2; ++ni) {
    const int col = bcol + ni * 16 + l16;
    const float bv = p.bias[l][col];
    const bool isz = col < H;  // uniform per 16-col group (16 | H)
    const int j = isz ? col : col - H;
#pragma unroll
    for (int mi = 0; mi < 2; ++mi)
#pragma unroll
      for (int r = 0; r < 4; ++r) {
        const int row = arow + mi * 16 + quad * 4 + r;
        const float s = sigmoidf_(acc[mi][ni][r] + bv);
        if (isz)
          p.zb[l][(size_t)row * H + j] = s;
        else
          p.rhFM[l][(size_t)(j >> 5) * 4096 + row * 32 + (j & 31)] =
              f2b(s * hfo[(size_t)row * H + j]);
      }
  }
}

// ---- n: n gate + h update + masked out accumulation. 56 blocks. ----
__global__ __launch_bounds__(512) void diag_n(DiagP p, int u) {
  const int blk = blockIdx.x;
  const int l = (blk < 8) ? 0 : ((blk < 24) ? 1 : 2);
  const int nt = blk - ((l == 0) ? 0 : ((l == 1) ? 8 : 24));
  const int t = u - l;
  if (t < 0 || t >= 128) return;
  const int H = 512 << l;
  const int inl = (l == 0) ? 512 : (512 << (l - 1));
  const int outoff = (l == 0) ? 0 : ((l == 1) ? 512 : 1536);
  const int oldS = (u + 1) & 1, newS = u & 1;

  const unsigned short* A1 =
      (l == 0) ? p.xFM + (size_t)t * 65536 : p.hFM[l - 1][oldS];

  const int tid = threadIdx.x, wave = tid >> 6;
  const int wg = wave >> 1, wc = wave & 1;
  const int arow = wg * 32;
  const int bcol = nt * 64 + wc * 32;

  f32x4 acc[2][2] = {};
  frag_gemm(A1, p.wnIh[l], inl >> 5, H * 32, arow, bcol, acc);
  frag_gemm(p.rhFM[l], p.wnHh[l], H >> 5, H * 32, arow, bcol, acc);

  const int lane = tid & 63, l16 = lane & 15, quad = lane >> 4;
  const float* hfo = p.hf[l][oldS];
  float* hfn = p.hf[l][newS];
  unsigned short* hFMn = p.hFM[l][newS];
#pragma unroll
  for (int ni = 0; ni < 2; ++ni) {
    const int col = bcol + ni * 16 + l16;
    const float bv = p.bias[l][2 * H + col];
#pragma unroll
    for (int mi = 0; mi < 2; ++mi)
#pragma unroll
      for (int r = 0; r < 4; ++r) {
        const int row = arow + mi * 16 + quad * 4 + r;
        const float nv = tanhf_(acc[mi][ni][r] + bv);
        const size_t idx = (size_t)row * H + col;
        const float z = p.zb[l][idx];
        const float hn = (1.0f - z) * nv + z * hfo[idx];
        hfn[idx] = hn;
        hFMn[(size_t)(col >> 5) * 4096 + row * 32 + (col & 31)] = f2b(hn);
        p.out[(size_t)row * 3584 + outoff + col] += p.mask[row * 128 + t] * hn;
      }
  }
}

// ---- prep: shuffle weights / x into fragment-major bf16 ----
// dst FM[kc][N][32] <- src rows [rowoff, rowoff+N) of [*, K] f32.
__global__ void shuf_w(const float* __restrict__ src,
                       unsigned short* __restrict__ dst, int N, int K,
                       int rowoff, int total) {
  int tid = blockIdx.x * 256 + threadIdx.x;
  if (tid >= total) return;
  int j = tid & 31;
  int rem = tid >> 5;
  int n = rem % N;
  int kc = rem / N;
  dst[tid] = f2b(src[(size_t)(rowoff + n) * K + kc * 32 + j]);
}

// x [B=128][T=128][I=512] f32 -> xFM [T][16][128][32] bf16.
__global__ void shuf_x(const float* __restrict__ x,
                       unsigned short* __restrict__ dst) {
  int tid = blockIdx.x * 256 + threadIdx.x;  // 8388608 total
  int j = tid & 31;
  int b = (tid >> 5) & 127;
  int kc = (tid >> 12) & 15;
  int t = tid >> 16;
  dst[tid] = f2b(x[((size_t)b * 128 + t) * 512 + kc * 32 + j]);
}

extern "C" void kernel_launch(void* const* d_in, const int* in_sizes, int n_in,
                              void* d_out, int out_size, void* d_ws,
                              size_t ws_size, hipStream_t stream) {
  const int B = 128, T = 128, I = 512;
  const int Hs[3] = {512, 1024, 2048};

  const float* x = (const float*)d_in[0];
  const float* mask = (const float*)d_in[1];
  const float* Wih[3] = {(const float*)d_in[2], (const float*)d_in[5],
                         (const float*)d_in[8]};
  const float* Whh[3] = {(const float*)d_in[3], (const float*)d_in[6],
                         (const float*)d_in[9]};
  const float* bias[3] = {(const float*)d_in[4], (const float*)d_in[7],
                          (const float*)d_in[10]};

  char* ws = (char*)d_ws;
  size_t off = 0;
  auto alloc = [&](size_t bytes) -> void* {
    void* p = ws + off;
    off = (off + bytes + 255) & ~(size_t)255;
    return p;
  };

  DiagP p;
  unsigned short* xFM = (unsigned short*)alloc((size_t)B * T * I * 2);
  unsigned short *wzrIh[3], *wzrHh[3], *wnIh[3], *wnHh[3];
  for (int l = 0; l < 3; ++l) {
    int H = Hs[l], inl = (l == 0) ? I : Hs[l - 1];
    wzrIh[l] = (unsigned short*)alloc((size_t)2 * H * inl * 2);
    wnIh[l] = (unsigned short*)alloc((size_t)H * inl * 2);
    wzrHh[l] = (unsigned short*)alloc((size_t)2 * H * H * 2);
    wnHh[l] = (unsigned short*)alloc((size_t)H * H * 2);
  }
  size_t hstart = off;
  for (int l = 0; l < 3; ++l)
    for (int s = 0; s < 2; ++s) p.hf[l][s] = (float*)alloc((size_t)B * Hs[l] * 4);
  for (int l = 0; l < 3; ++l)
    for (int s = 0; s < 2; ++s)
      p.hFM[l][s] = (unsigned short*)alloc((size_t)B * Hs[l] * 2);
  size_t hend = off;
  for (int l = 0; l < 3; ++l) p.zb[l] = (float*)alloc((size_t)B * Hs[l] * 4);
  for (int l = 0; l < 3; ++l)
    p.rhFM[l] = (unsigned short*)alloc((size_t)B * Hs[l] * 2);
  (void)ws_size;

  p.xFM = xFM;
  for (int l = 0; l < 3; ++l) {
    p.wzrIh[l] = wzrIh[l];
    p.wzrHh[l] = wzrHh[l];
    p.wnIh[l] = wnIh[l];
    p.wnHh[l] = wnHh[l];
    p.bias[l] = bias[l];
  }
  p.mask = mask;
  p.out = (float*)d_out;

  // ---- prep ----
  shuf_x<<<(B * T * I) / 256, 256, 0, stream>>>(x, xFM);
  auto shw = [&](const float* src, unsigned short* dst, int N, int K,
                 int rowoff) {
    int total = N * K;
    shuf_w<<<(total + 255) / 256, 256, 0, stream>>>(src, dst, N, K, rowoff,
                                                    total);
  };
  for (int l = 0; l < 3; ++l) {
    int H = Hs[l], inl = (l == 0) ? I : Hs[l - 1];
    shw(Wih[l], wzrIh[l], 2 * H, inl, 0);
    shw(Wih[l], wnIh[l], H, inl, 2 * H);
    shw(Whh[l], wzrHh[l], 2 * H, H, 0);
    shw(Whh[l], wnHh[l], H, H, 2 * H);
  }
  hipMemsetAsync(ws + hstart, 0, hend - hstart, stream);
  hipMemsetAsync(d_out, 0, (size_t)out_size * 4, stream);

  // ---- diagonal scan: tick u covers (l, t=u-l) ----
  for (int u = 0; u < T + 2; ++u) {
    diag_zr<<<112, 512, 0, stream>>>(p, u);
    diag_n<<<56, 512, 0, stream>>>(p, u);
  }
}